// Round 4
// baseline (57.356 us; speedup 1.0000x reference)
//
#include <hip/hip_runtime.h>

#define WORKERS 2048
#define TASKS   2048
#define ETYPE   16
#define ABIL    64

#define F4_PER_WORKER  8192               // 32768 floats per worker / 4
#define ITERS          32                 // 8192 f4 / 256 threads

typedef float f4 __attribute__((ext_vector_type(4)));   // native vec: ok for nt-store

// ---------------------------------------------------------------------------
// Single fused kernel, one worker per block (2048 blocks = 8 blocks/CU).
// Every thread redundantly computes the worker's l1=log2(p1), l2=log2(p2)
// (block-uniform addresses -> scalar loads), then streams 32 lane-contiguous
// float4 nontemporal stores (writes are never re-read; nt keeps L2 warm for
// the tau re-reads).
//   P[w][t][e] = exp2( tau[t][e]*l1 + (1-tau[t][e])*l2 )
// Two-term exponent form keeps the p1->1 (l2=-inf) case producing exact 0.
// #pragma unroll 4 caps in-flight tau registers so VGPR stays <=64 and the
// whole grid is co-resident (32 waves/CU) for max outstanding stores.
// ---------------------------------------------------------------------------
__global__ void __launch_bounds__(256)
fused_kernel(const float* __restrict__ inputs,
             const float* __restrict__ W,
             const float* __restrict__ b,
             f4* __restrict__ out) {
    const int w = blockIdx.x;             // worker index, block-uniform

    // --- per-worker scalars (redundant per thread, block-uniform) ---
    const f4* row = reinterpret_cast<const f4*>(inputs + (size_t)w * ABIL);
    const f4* Wv  = reinterpret_cast<const f4*>(W);
    float acc = 0.0f;
#pragma unroll
    for (int k = 0; k < ABIL / 4; ++k) {
        f4 x  = row[k];
        f4 wv = Wv[k];
        acc = fmaf(x.x, wv.x, acc);
        acc = fmaf(x.y, wv.y, acc);
        acc = fmaf(x.z, wv.z, acc);
        acc = fmaf(x.w, wv.w, acc);
    }
    acc += b[0];
    const float LOG2E = 1.4426950408889634f;
    float e  = __builtin_amdgcn_exp2f(-acc * LOG2E);
    float p1 = 1.0f / (1.0f + e);
    float p2 = (1.0f - p1) * (1.0f / (ETYPE - 1));
    const float a = __builtin_amdgcn_logf(p1);   // v_log_f32 = log2
    const float c = __builtin_amdgcn_logf(p2);

    // --- stream 32 float4 outputs, lane-contiguous per instruction ---
    const int base = w * F4_PER_WORKER + (int)threadIdx.x;
#pragma unroll 4
    for (int it = 0; it < ITERS; ++it) {
        const int i    = base + it * 256;
        const int rem4 = i & (F4_PER_WORKER - 1);     // = it*256 + tid
        const int t    = rem4 >> 2;                   // task index
        const int e0   = (rem4 & 3) * 4;              // edge-type offset
        const f4 tau = *reinterpret_cast<const f4*>(
            inputs + (size_t)(WORKERS + t) * ABIL + e0);   // L2-resident
        f4 r;
        r.x = __builtin_amdgcn_exp2f(fmaf(tau.x, a, (1.0f - tau.x) * c));
        r.y = __builtin_amdgcn_exp2f(fmaf(tau.y, a, (1.0f - tau.y) * c));
        r.z = __builtin_amdgcn_exp2f(fmaf(tau.z, a, (1.0f - tau.z) * c));
        r.w = __builtin_amdgcn_exp2f(fmaf(tau.w, a, (1.0f - tau.w) * c));
        __builtin_nontemporal_store(r, &out[i]);
    }
}

extern "C" void kernel_launch(void* const* d_in, const int* in_sizes, int n_in,
                              void* d_out, int out_size, void* d_ws, size_t ws_size,
                              hipStream_t stream) {
    const float* inputs = (const float*)d_in[0];
    const float* W      = (const float*)d_in[1];
    const float* b      = (const float*)d_in[2];

    fused_kernel<<<WORKERS, 256, 0, stream>>>(inputs, W, b, (f4*)d_out);
}

// Round 5
// 47.618 us; speedup vs baseline: 1.2045x; 1.2045x over previous
//
#include <hip/hip_runtime.h>

#define WORKERS 2048
#define TASKS   2048
#define ETYPE   16
#define ABIL    64

#define F4_PER_WORKER 8192            // 32768 floats / 4
#define TE_BLOCKS     32              // 8192 f4 of (t,e) space / 256 threads
#define W_PER_BLOCK   32
#define NBLOCKS ((WORKERS / W_PER_BLOCK) * TE_BLOCKS)   // 64 * 32 = 2048

typedef float f4 __attribute__((ext_vector_type(4)));

// ---------------------------------------------------------------------------
// Store-stream kernel: each block owns a 256-float4 slice of (t,e) space and
// 32 workers. tau for the slice is loaded ONCE per thread into registers;
// the 32 workers' (l1,l2) are computed cooperatively into LDS in the
// prologue. Steady state = {2 broadcast LDS reads + 12 VALU + 1 coalesced
// 16B store} per iteration — zero global loads, structurally a fill kernel.
//   P[w][t][e] = exp2( tau*l1[w] + (1-tau)*l2[w] )
// Two-term exponent keeps the p1->1 (l2=-inf) case producing exact 0.
// Regular stores (nt bypassed L2 and regressed 46->57 us in round 4).
// ---------------------------------------------------------------------------
__global__ void __launch_bounds__(256)
stream_kernel(const float* __restrict__ inputs,
              const float* __restrict__ W,
              const float* __restrict__ bb,
              f4* __restrict__ out) {
    __shared__ float sA[W_PER_BLOCK];
    __shared__ float sC[W_PER_BLOCK];

    const int tid    = threadIdx.x;
    const int blk    = blockIdx.x;
    const int te_grp = blk & (TE_BLOCKS - 1);   // which 256-f4 (t,e) slice
    const int wgrp   = blk >> 5;                // which 32-worker group
    const int w0     = wgrp * W_PER_BLOCK;

    // --- issue tau load early (one f4 per thread, register-resident) ---
    const int te  = te_grp * 256 + tid;         // f4 index in (t,e) space
    const int t   = te >> 2;
    const int e0  = (te & 3) * 4;
    const f4 tau  = *reinterpret_cast<const f4*>(
        inputs + (size_t)(WORKERS + t) * ABIL + e0);

    // --- prologue: 32 worker dots, 8 threads per worker ---
    {
        const int lw = tid >> 3;                // local worker 0..31
        const int ch = tid & 7;                 // 8-float chunk of the dot
        const f4* rv = reinterpret_cast<const f4*>(
            inputs + (size_t)(w0 + lw) * ABIL + ch * 8);
        const f4* Wv = reinterpret_cast<const f4*>(W + ch * 8);
        f4 x0 = rv[0], x1 = rv[1];
        f4 y0 = Wv[0], y1 = Wv[1];
        float acc = 0.0f;
        acc = fmaf(x0.x, y0.x, acc); acc = fmaf(x0.y, y0.y, acc);
        acc = fmaf(x0.z, y0.z, acc); acc = fmaf(x0.w, y0.w, acc);
        acc = fmaf(x1.x, y1.x, acc); acc = fmaf(x1.y, y1.y, acc);
        acc = fmaf(x1.z, y1.z, acc); acc = fmaf(x1.w, y1.w, acc);
        // reduce across the 8-lane group (stays inside one wave)
        acc += __shfl_xor(acc, 1, 64);
        acc += __shfl_xor(acc, 2, 64);
        acc += __shfl_xor(acc, 4, 64);
        if (ch == 0) {
            acc += bb[0];
            const float LOG2E = 1.4426950408889634f;
            float e  = __builtin_amdgcn_exp2f(-acc * LOG2E);
            float p1 = 1.0f / (1.0f + e);
            float p2 = (1.0f - p1) * (1.0f / (ETYPE - 1));
            sA[lw] = __builtin_amdgcn_logf(p1);   // v_log_f32 = log2
            sC[lw] = __builtin_amdgcn_logf(p2);
        }
    }
    __syncthreads();

    // --- steady state: one coalesced f4 store per worker, no global loads ---
    f4* outp = out + (size_t)w0 * F4_PER_WORKER + te;
#pragma unroll 8
    for (int lw = 0; lw < W_PER_BLOCK; ++lw) {
        const float a = sA[lw];   // broadcast LDS read
        const float c = sC[lw];
        f4 r;
        r.x = __builtin_amdgcn_exp2f(fmaf(tau.x, a, (1.0f - tau.x) * c));
        r.y = __builtin_amdgcn_exp2f(fmaf(tau.y, a, (1.0f - tau.y) * c));
        r.z = __builtin_amdgcn_exp2f(fmaf(tau.z, a, (1.0f - tau.z) * c));
        r.w = __builtin_amdgcn_exp2f(fmaf(tau.w, a, (1.0f - tau.w) * c));
        outp[(size_t)lw * F4_PER_WORKER] = r;
    }
}

extern "C" void kernel_launch(void* const* d_in, const int* in_sizes, int n_in,
                              void* d_out, int out_size, void* d_ws, size_t ws_size,
                              hipStream_t stream) {
    const float* inputs = (const float*)d_in[0];
    const float* W      = (const float*)d_in[1];
    const float* b      = (const float*)d_in[2];

    stream_kernel<<<NBLOCKS, 256, 0, stream>>>(inputs, W, b, (f4*)d_out);
}